// Round 4
// baseline (3824.237 us; speedup 1.0000x reference)
//
#include <hip/hip_runtime.h>
#include <hip/hip_bf16.h>

typedef __bf16 bf16;
typedef __bf16 bf16x8 __attribute__((ext_vector_type(8)));
typedef float f32x4 __attribute__((ext_vector_type(4)));
typedef unsigned long long u64;
typedef u64 u64x2 __attribute__((ext_vector_type(2)));

#define B_ 16
#define T_ 241
#define H_ 1024
#define NC_ 100
#define TE_ 512
#define BT_ 3856   // B_*T_
#define OUT0_ 385600
#define OUT1_ 7897088
#define SEGCAP_ 3872

// ---------------- utility kernels ----------------

__global__ void zero_fill(unsigned* __restrict__ p, long n) {
    for (long i = (long)blockIdx.x * blockDim.x + threadIdx.x; i < n;
         i += (long)gridDim.x * blockDim.x) p[i] = 0u;
}

__global__ void bias_sum(const float* a0, const float* b0, const float* a1,
                         const float* b1, float* o0, float* o1) {
    int i = blockIdx.x * blockDim.x + threadIdx.x;
    if (i < 4096) { o0[i] = a0[i] + b0[i]; o1[i] = a1[i] + b1[i]; }
}

__global__ void f2bf(const float* __restrict__ in, bf16* __restrict__ out, long n) {
    for (long i = (long)blockIdx.x * blockDim.x + threadIdx.x; i < n;
         i += (long)gridDim.x * blockDim.x) out[i] = (bf16)in[i];
}

__global__ void embed_gather(const int* __restrict__ tg, const float* __restrict__ embw,
                             bf16* __restrict__ out, long n) {
    for (long i = (long)blockIdx.x * blockDim.x + threadIdx.x; i < n;
         i += (long)gridDim.x * blockDim.x) {
        int bt = (int)(i >> 10), d = (int)(i & 1023);
        out[i] = (bf16)embw[(long)tg[bt] * H_ + d];
    }
}

__global__ void pack_w1(const float* __restrict__ wih, const float* __restrict__ whh,
                        bf16* __restrict__ out) {
    long n = (long)4096 * 2048;
    for (long i = (long)blockIdx.x * blockDim.x + threadIdx.x; i < n;
         i += (long)gridDim.x * blockDim.x) {
        int r = (int)(i >> 11), k = (int)(i & 2047);
        float v = (k < 1024) ? wih[(long)r * 1024 + k] : whh[(long)r * 1024 + (k - 1024)];
        out[i] = (bf16)v;
    }
}

// out[n][k] = in[k][n], n < Cp (zero pad beyond C)
__global__ void transpose_bf16(const float* __restrict__ in, bf16* __restrict__ out,
                               int R, int C, int Cp) {
    __shared__ float tile[32][33];
    int k0 = blockIdx.x * 32, n0 = blockIdx.y * 32;
    int tx = threadIdx.x & 31, ty = threadIdx.x >> 5;  // 32x8
    for (int yy = ty; yy < 32; yy += 8) {
        int k = k0 + yy, n = n0 + tx;
        tile[yy][tx] = (k < R && n < C) ? in[(long)k * C + n] : 0.f;
    }
    __syncthreads();
    for (int yy = ty; yy < 32; yy += 8) {
        int n = n0 + yy, k = k0 + tx;
        if (n < Cp && k < R) out[(long)n * R + k] = (bf16)tile[tx][yy];
    }
}

// ---------------- generic A(row-major bf16) x Bt(row-major bf16) GEMM ----------------

struct GemmArgs {
    const bf16* A; long sAb; long sAh; int lda;
    const bf16* Bt; long sBb; long sBh; int ldb;
    float* C; long sCb; long sCh; int ldc;
    bf16* Cb; long sCbb; long sCbh; int ldcb;
    const float* biasCol; const float* biasRow;
    int M; int N; int K; int nh; int act;
};

__global__ void __launch_bounds__(256) gemm_bt(GemmArgs g) {
    int z = blockIdx.z;
    int zb = z / g.nh, zh = z - zb * g.nh;
    const bf16* A  = g.A  + (long)zb * g.sAb + (long)zh * g.sAh;
    const bf16* Bt = g.Bt + (long)zb * g.sBb + (long)zh * g.sBh;
    int wave = threadIdx.x >> 6, lane = threadIdx.x & 63;
    int l15 = lane & 15, kb = (lane >> 4) * 8;
    int mt0 = blockIdx.y * 4 + (wave >> 1) * 2;
    int ct0 = blockIdx.x * 4 + (wave & 1) * 2;
    const bf16* pa0 = A + (long)(mt0 * 16 + l15) * g.lda + kb;
    const bf16* pa1 = pa0 + (long)16 * g.lda;
    const bf16* pb0 = Bt + (long)(ct0 * 16 + l15) * g.ldb + kb;
    const bf16* pb1 = pb0 + (long)16 * g.ldb;
    f32x4 acc00 = {0.f,0.f,0.f,0.f}, acc01 = {0.f,0.f,0.f,0.f};
    f32x4 acc10 = {0.f,0.f,0.f,0.f}, acc11 = {0.f,0.f,0.f,0.f};
    for (int k = 0; k < g.K; k += 32) {
        bf16x8 a0 = *(const bf16x8*)(pa0 + k);
        bf16x8 a1 = *(const bf16x8*)(pa1 + k);
        bf16x8 b0 = *(const bf16x8*)(pb0 + k);
        bf16x8 b1 = *(const bf16x8*)(pb1 + k);
        acc00 = __builtin_amdgcn_mfma_f32_16x16x32_bf16(a0, b0, acc00, 0, 0, 0);
        acc01 = __builtin_amdgcn_mfma_f32_16x16x32_bf16(a0, b1, acc01, 0, 0, 0);
        acc10 = __builtin_amdgcn_mfma_f32_16x16x32_bf16(a1, b0, acc10, 0, 0, 0);
        acc11 = __builtin_amdgcn_mfma_f32_16x16x32_bf16(a1, b1, acc11, 0, 0, 0);
    }
    float* C  = g.C  ? g.C  + (long)zb * g.sCb  + (long)zh * g.sCh  : (float*)0;
    bf16*  Cb = g.Cb ? g.Cb + (long)zb * g.sCbb + (long)zh * g.sCbh : (bf16*)0;
    int rbase = (lane >> 4) * 4;
#pragma unroll
    for (int i = 0; i < 2; i++) {
#pragma unroll
        for (int j = 0; j < 2; j++) {
            f32x4 av = i ? (j ? acc11 : acc10) : (j ? acc01 : acc00);
            int colg = (ct0 + j) * 16 + l15;
            if (colg >= g.N) continue;
            float bc = g.biasCol ? g.biasCol[colg] : 0.f;
#pragma unroll
            for (int r = 0; r < 4; r++) {
                int rowg = (mt0 + i) * 16 + rbase + r;
                if (rowg >= g.M) continue;
                float val = av[r] + bc;
                if (g.biasRow) val += g.biasRow[rowg];
                if (g.act == 1) val = tanhf(val);
                if (C)  C[(long)rowg * g.ldc + colg] = val;
                if (Cb) Cb[(long)rowg * g.ldcb + colg] = (bf16)val;
            }
        }
    }
}

// ---------------- persistent LSTM recurrence (decoupled layers) ----------------
// blocks 0..127: layer0 (8 units each); 128..255: layer1.
// h0 -> per-step history (write-once slots, no WAR). L0 syncs only with L0;
// L1 waits on L0 progress (usually already ahead) + L1 peers.
// flags[0..127]=L0 progress, flags[128..255]=L1 progress. Dense 4B flags.

__device__ __forceinline__ u64 cload(const u64* p) {
    return __hip_atomic_load(p, __ATOMIC_RELAXED, __HIP_MEMORY_SCOPE_AGENT);
}
__device__ __forceinline__ void cstore(unsigned* p, unsigned v) {
    __hip_atomic_store(p, v, __ATOMIC_RELAXED, __HIP_MEMORY_SCOPE_AGENT);
}
__device__ __forceinline__ unsigned pack2(bf16 a, bf16 b) {
    union { bf16 h[2]; unsigned u; } x; x.h[0] = a; x.h[1] = b; return x.u;
}
__device__ __forceinline__ unsigned fload(const unsigned* p) {
    return __hip_atomic_load(p, __ATOMIC_RELAXED, __HIP_MEMORY_SCOPE_AGENT);
}

// wave-cooperative: wait until all f0[0..127] >= t0 (and f1[0..127] >= t1 if f1)
__device__ __forceinline__ void pollf(const unsigned* f0, unsigned t0,
                                      const unsigned* f1, unsigned t1, int lane) {
    for (;;) {
        unsigned a = fload(f0 + 2 * lane);
        unsigned b = fload(f0 + 2 * lane + 1);
        bool ok = (a >= t0) && (b >= t0);
        if (f1) {
            unsigned c = fload(f1 + 2 * lane);
            unsigned d = fload(f1 + 2 * lane + 1);
            ok = ok && (c >= t1) && (d >= t1);
        }
        if (__all((int)ok)) break;
        __builtin_amdgcn_s_sleep(1);
    }
    asm volatile("" ::: "memory");
}

__global__ void __launch_bounds__(256, 1) lstm_persist(
    const bf16* __restrict__ Whh0, const bf16* __restrict__ W1pk,
    const float* __restrict__ xg0, const float* __restrict__ bias1,
    bf16* __restrict__ h0hist,      // [242][16][1024], slot0 zeroed
    bf16* __restrict__ h1buf,       // [2][16][1024], zeroed
    bf16* __restrict__ featsA, unsigned* __restrict__ flags) {
    int blk = blockIdx.x;
    bool isL1 = blk >= 128;
    int bL = isL1 ? blk - 128 : blk;
    int ub = bL * 8;
    int wave = threadIdx.x >> 6, lane = threadIdx.x & 63;
    int l15 = lane & 15, kb = (lane >> 4) * 8;
    int rl0 = l15, rl1 = 16 + l15;
    int grow0 = (rl0 >> 3) * 1024 + ub + (rl0 & 7);
    int grow1 = (rl1 >> 3) * 1024 + ub + (rl1 & 7);

    __shared__ float red[4][32][17];

    int t = threadIdx.x;
    int pb = t >> 2, up = (t & 3) * 2;        // pointwise: 64 threads, 2 units
    float cr0 = 0.f, cr1 = 0.f;
    int rb = (lane >> 4) * 4;

    if (!isL1) {
        f32x4 wa[8], wb[8];
        const bf16* p0 = Whh0 + (long)grow0 * 1024 + wave * 256 + kb;
        const bf16* p1 = Whh0 + (long)grow1 * 1024 + wave * 256 + kb;
#pragma unroll
        for (int i = 0; i < 8; i++) {
            wa[i] = *(const f32x4*)(p0 + 32 * i);
            wb[i] = *(const f32x4*)(p1 + 32 * i);
            asm volatile("" : "+v"(wa[i]), "+v"(wb[i]));
        }
        for (int s = 0; s < 241; s++) {
            if (s) pollf(flags, (unsigned)s, (const unsigned*)0, 0u, lane);
            const bf16* pa = h0hist + (long)s * 16384 + l15 * 1024 + wave * 256 + kb;
            u64x2 hf[8];
#pragma unroll
            for (int i = 0; i < 8; i++) {
                const u64* q = (const u64*)(pa + 32 * i);
                hf[i].x = cload(q); hf[i].y = cload(q + 1);
            }
            f32x4 acc0 = {0.f,0.f,0.f,0.f}, acc1 = {0.f,0.f,0.f,0.f};
#pragma unroll
            for (int i = 0; i < 8; i++) {
                bf16x8 a = __builtin_bit_cast(bf16x8, hf[i]);
                acc0 = __builtin_amdgcn_mfma_f32_16x16x32_bf16(a, __builtin_bit_cast(bf16x8, wa[i]), acc0, 0, 0, 0);
                acc1 = __builtin_amdgcn_mfma_f32_16x16x32_bf16(a, __builtin_bit_cast(bf16x8, wb[i]), acc1, 0, 0, 0);
            }
#pragma unroll
            for (int r = 0; r < 4; r++) {
                red[wave][rl0][rb + r] = acc0[r];
                red[wave][rl1][rb + r] = acc1[r];
            }
            __syncthreads();
            if (t < 64) {
                float g[2][4];
#pragma unroll
                for (int uu = 0; uu < 2; uu++)
#pragma unroll
                    for (int gi = 0; gi < 4; gi++) {
                        float v = 0.f;
#pragma unroll
                        for (int w = 0; w < 4; w++) v += red[w][gi * 8 + up + uu][pb];
                        g[uu][gi] = v;
                    }
                const float* xp = xg0 + ((long)pb * 241 + s) * 4096 + ub + up;
                bf16 hv[2];
#pragma unroll
                for (int uu = 0; uu < 2; uu++) {
                    float gi_ = g[uu][0] + xp[uu];
                    float gf_ = g[uu][1] + xp[1024 + uu];
                    float gg_ = g[uu][2] + xp[2048 + uu];
                    float go_ = g[uu][3] + xp[3072 + uu];
                    float si = 1.f / (1.f + expf(-gi_));
                    float sf = 1.f / (1.f + expf(-gf_));
                    float so = 1.f / (1.f + expf(-go_));
                    float& cr = uu ? cr1 : cr0;
                    cr = sf * cr + si * tanhf(gg_);
                    hv[uu] = (bf16)(so * tanhf(cr));
                }
                cstore((unsigned*)(h0hist + (long)(s + 1) * 16384 + pb * 1024 + ub + up),
                       pack2(hv[0], hv[1]));
                asm volatile("s_waitcnt vmcnt(0)" ::: "memory");
                if (t == 0) cstore(flags + blk, (unsigned)(s + 1));
            }
        }
    } else {
        f32x4 wa[16], wb[16];
        const bf16* p0 = W1pk + (long)grow0 * 2048 + wave * 512 + kb;
        const bf16* p1 = W1pk + (long)grow1 * 2048 + wave * 512 + kb;
#pragma unroll
        for (int i = 0; i < 16; i++) {
            wa[i] = *(const f32x4*)(p0 + 32 * i);
            wb[i] = *(const f32x4*)(p1 + 32 * i);
            asm volatile("" : "+v"(wa[i]), "+v"(wb[i]));
        }
        for (int s = 1; s <= 241; s++) {
            pollf(flags, (unsigned)s, flags + 128, (unsigned)(s - 1), lane);
            // A rows: [h0(time s-1) | h1(time s-2)]; waves 0-1 read h0hist[s],
            // waves 2-3 read h1buf[s&1]
            const bf16* pa = (wave < 2)
                ? h0hist + (long)s * 16384 + l15 * 1024 + wave * 512 + kb
                : h1buf + (long)((s & 1) << 14) + l15 * 1024 + (wave - 2) * 512 + kb;
            u64x2 hf[16];
#pragma unroll
            for (int i = 0; i < 16; i++) {
                const u64* q = (const u64*)(pa + 32 * i);
                hf[i].x = cload(q); hf[i].y = cload(q + 1);
            }
            f32x4 acc0 = {0.f,0.f,0.f,0.f}, acc1 = {0.f,0.f,0.f,0.f};
#pragma unroll
            for (int i = 0; i < 16; i++) {
                bf16x8 a = __builtin_bit_cast(bf16x8, hf[i]);
                acc0 = __builtin_amdgcn_mfma_f32_16x16x32_bf16(a, __builtin_bit_cast(bf16x8, wa[i]), acc0, 0, 0, 0);
                acc1 = __builtin_amdgcn_mfma_f32_16x16x32_bf16(a, __builtin_bit_cast(bf16x8, wb[i]), acc1, 0, 0, 0);
            }
#pragma unroll
            for (int r = 0; r < 4; r++) {
                red[wave][rl0][rb + r] = acc0[r];
                red[wave][rl1][rb + r] = acc1[r];
            }
            __syncthreads();
            if (t < 64) {
                float g[2][4];
#pragma unroll
                for (int uu = 0; uu < 2; uu++)
#pragma unroll
                    for (int gi = 0; gi < 4; gi++) {
                        float v = 0.f;
#pragma unroll
                        for (int w = 0; w < 4; w++) v += red[w][gi * 8 + up + uu][pb];
                        g[uu][gi] = v;
                    }
                bf16 hv[2];
#pragma unroll
                for (int uu = 0; uu < 2; uu++) {
                    float gi_ = g[uu][0] + bias1[ub + up + uu];
                    float gf_ = g[uu][1] + bias1[1024 + ub + up + uu];
                    float gg_ = g[uu][2] + bias1[2048 + ub + up + uu];
                    float go_ = g[uu][3] + bias1[3072 + ub + up + uu];
                    float si = 1.f / (1.f + expf(-gi_));
                    float sf = 1.f / (1.f + expf(-gf_));
                    float so = 1.f / (1.f + expf(-go_));
                    float& cr = uu ? cr1 : cr0;
                    cr = sf * cr + si * tanhf(gg_);
                    hv[uu] = (bf16)(so * tanhf(cr));
                }
                unsigned pv = pack2(hv[0], hv[1]);
                cstore((unsigned*)(h1buf + (long)(((s + 1) & 1) << 14) + pb * 1024 + ub + up), pv);
                *(unsigned*)(featsA + ((long)pb * 241 + (s - 1)) * 2048 + ub + up) = pv;
                asm volatile("s_waitcnt vmcnt(0)" ::: "memory");
                if (t == 0) cstore(flags + blk, (unsigned)s);
            }
        }
    }
}

// ---------------- softmaxes ----------------

__global__ void __launch_bounds__(256) attn_softmax(float* __restrict__ attn,
                                                    bf16* __restrict__ attnb, int nrows) {
    int row = blockIdx.x * 4 + (threadIdx.x >> 6);
    int lane = threadIdx.x & 63;
    if (row >= nrows) return;
    float* p = attn + (long)row * 512;
    float v[8];
    float m = -1e30f;
#pragma unroll
    for (int j = 0; j < 8; j++) { v[j] = p[lane + 64 * j] * 0.0625f; m = fmaxf(m, v[j]); }
    for (int o = 32; o; o >>= 1) m = fmaxf(m, __shfl_xor(m, o));
    float ssum = 0.f;
#pragma unroll
    for (int j = 0; j < 8; j++) { v[j] = expf(v[j] - m); ssum += v[j]; }
    for (int o = 32; o; o >>= 1) ssum += __shfl_xor(ssum, o);
    float inv = 1.f / ssum;
#pragma unroll
    for (int j = 0; j < 8; j++) {
        float a = v[j] * inv;
        p[lane + 64 * j] = a;
        attnb[(long)row * 512 + lane + 64 * j] = (bf16)a;
    }
}

__global__ void __launch_bounds__(256) logsoftmax_k(float* __restrict__ out, int nrows) {
    int row = blockIdx.x * 4 + (threadIdx.x >> 6);
    int lane = threadIdx.x & 63;
    if (row >= nrows) return;
    float* p = out + (long)row * 100;
    float v0 = lane < 100 ? p[lane] : -1e30f;
    float v1 = lane < 36 ? p[64 + lane] : -1e30f;
    float m = fmaxf(v0, v1);
    for (int o = 32; o; o >>= 1) m = fmaxf(m, __shfl_xor(m, o));
    float s = (lane < 100 ? expf(v0 - m) : 0.f) + (lane < 36 ? expf(v1 - m) : 0.f);
    for (int o = 32; o; o >>= 1) s += __shfl_xor(s, o);
    float lg = m + logf(s);
    if (lane < 100) p[lane] = v0 - lg;
    if (lane < 36) p[64 + lane] = v1 - lg;
}

// ---------------- words ----------------

__global__ void seg_scan(const int* __restrict__ tg, int* __restrict__ meta) {
    __shared__ int st[16][242], ln[16][242];
    __shared__ int cnt[16], rmax[16], off[17];
    int b = threadIdx.x;
    if (b < 16) {
        const int* tok = tg + b * 241 + 1;
        int start = 0, n = 0, mx = 0; bool broke = false;
        for (int t = 0; t < 240; t++) {
            int v = tok[t];
            if (v == 1 || v == 2) {
                st[b][n] = start; ln[b][n] = t - start;
                if (t - start > mx) mx = t - start;
                n++; start = t + 1;
                if (v == 2) { broke = true; break; }
            }
        }
        if (!broke && start < 240) {
            st[b][n] = start; ln[b][n] = 240 - start;
            if (240 - start > mx) mx = 240 - start;
            n++;
        }
        cnt[b] = n; rmax[b] = mx;
    }
    __syncthreads();
    if (threadIdx.x == 0) {
        int tot = 0, mx = 0;
        for (int i = 0; i < 16; i++) { off[i] = tot; tot += cnt[i]; if (rmax[i] > mx) mx = rmax[i]; }
        off[16] = tot; meta[0] = tot; meta[1] = mx;
    }
    __syncthreads();
    if (b < 16) {
        int* segb = meta + 2; int* segs = segb + SEGCAP_; int* segl = segs + SEGCAP_;
        int o = off[b];
        for (int i = 0; i < cnt[b]; i++) { segb[o + i] = b; segs[o + i] = st[b][i]; segl[o + i] = ln[b][i]; }
    }
}

__global__ void words_fill(const int* __restrict__ meta, const int* __restrict__ tg,
                           const float* __restrict__ embw, const float* __restrict__ ctxf,
                           float* __restrict__ out2, long nelem) {
    int N = meta[0], mx = meta[1];
    const int* segb = meta + 2;
    const int* segs = segb + SEGCAP_;
    const int* segl = segs + SEGCAP_;
    unsigned wl = (unsigned)mx * 2048u;
    if (wl == 0) wl = 1u;
    for (long ee = (long)blockIdx.x * blockDim.x + threadIdx.x; ee < nelem;
         ee += (long)gridDim.x * blockDim.x) {
        unsigned e = (unsigned)ee;
        unsigned n = e / wl, rem = e - n * wl;
        unsigned l = rem >> 11, d = rem & 2047u;
        float val = 0.f;
        if ((int)n < N && (int)l < segl[n]) {
            int b = segb[n]; int tp = segs[n] + (int)l;  // index in sliced [0,240)
            if (d < 1024u) val = embw[(long)tg[b * 241 + tp + 1] * H_ + d];
            else val = ctxf[((long)b * 241 + tp) * H_ + (d - 1024u)];
        }
        out2[ee] = val;
    }
}

// ---------------- host ----------------

extern "C" void kernel_launch(void* const* d_in, const int* in_sizes, int n_in,
                              void* d_out, int out_size, void* d_ws, size_t ws_size,
                              hipStream_t stream) {
    const int*   targets = (const int*)d_in[0];
    const float* enc  = (const float*)d_in[1];
    const float* embw = (const float*)d_in[2];
    const float* wih0 = (const float*)d_in[3];
    const float* whh0 = (const float*)d_in[4];
    const float* bih0 = (const float*)d_in[5];
    const float* bhh0 = (const float*)d_in[6];
    const float* wih1 = (const float*)d_in[7];
    const float* whh1 = (const float*)d_in[8];
    const float* bih1 = (const float*)d_in[9];
    const float* bhh1 = (const float*)d_in[10];
    const float* wq = (const float*)d_in[11];
    const float* bq = (const float*)d_in[12];
    const float* wk = (const float*)d_in[13];
    const float* bk = (const float*)d_in[14];
    const float* wv = (const float*)d_in[15];
    const float* bv = (const float*)d_in[16];
    const float* w1 = (const float*)d_in[17];
    const float* b1 = (const float*)d_in[18];
    const float* w2 = (const float*)d_in[19];
    const float* b2 = (const float*)d_in[20];

    char* ws = (char*)d_ws;
    size_t off = 0;
    auto alloc = [&](size_t bytes) {
        char* p = ws + off; off += (bytes + 255) & ~(size_t)255; return p;
    };
    // zero-init region (contiguous): flags, h1buf, h0hist[0]
    unsigned* flags = (unsigned*)alloc(1024);                 // 256 dense flags
    bf16* h1buf  = (bf16*)alloc(2 * 16 * 1024 * 2);           // 64 KB
    bf16* h0hist = (bf16*)alloc((size_t)242 * 16 * 1024 * 2); // 7.9 MB
    float* bias0 = (float*)alloc(16384);
    float* bias1f = (float*)alloc(16384);
    int* meta = (int*)alloc((2 + 3 * SEGCAP_) * 4);
    bf16* kbf = (bf16*)alloc((size_t)8192 * 1024 * 2);
    bf16* wqT = (bf16*)alloc((size_t)1024 * 1024 * 2);
    bf16* w1T = (bf16*)alloc((size_t)1024 * 2048 * 2);
    bf16* w2T = (bf16*)alloc((size_t)128 * 1024 * 2);
    bf16* featsA = (bf16*)alloc((size_t)3920 * 2048 * 2);
    char* regB = alloc(63176704);              // xg0; reused after recurrence
    float* xg0  = (float*)regB;
    bf16* qbf   = (bf16*)regB;                           // 3920*1024*2 = 8028160
    bf16* attnb = (bf16*)(regB + 8028160);               // 15488*512*2 = 15859712
    float* ctxf = (float*)(regB + 8028160 + 15859712);   // 3856*1024*4 = 15794176
    bf16* xbf   = (bf16*)(regB + 39682048);              // 3920*1024*2
    bf16* embb  = (bf16*)alloc((size_t)3920 * 1024 * 2);
    bf16* encb  = (bf16*)alloc((size_t)8192 * 1024 * 2);
    bf16* wih0b = (bf16*)alloc((size_t)4096 * 1024 * 2);
    bf16* whh0b = (bf16*)alloc((size_t)4096 * 1024 * 2);
    bf16* w1pk  = (bf16*)alloc((size_t)4096 * 2048 * 2);
    bf16* wkT = (bf16*)alloc((size_t)1024 * 1024 * 2);
    bf16* wvT = (bf16*)alloc((size_t)1024 * 1024 * 2);
    // vT (16 MB) reuses wih0b+whh0b after the recurrence (both dead by then)
    bf16* vT = wih0b;
    (void)ws_size; (void)in_sizes; (void)n_in;

    auto gemm = [&](const bf16* A, long sAb, long sAh, int lda,
                    const bf16* Bt, long sBb, long sBh, int ldb,
                    float* C, long sCb, long sCh, int ldc,
                    bf16* Cb, long sCbb, long sCbh, int ldcb,
                    const float* bc, const float* br,
                    int M, int N, int K, int nh, int act, int Z) {
        GemmArgs ga{A, sAb, sAh, lda, Bt, sBb, sBh, ldb, C, sCb, sCh, ldc,
                    Cb, sCbb, sCbh, ldcb, bc, br, M, N, K, nh, act};
        dim3 grid((N + 63) / 64, (M + 63) / 64, Z);
        gemm_bt<<<grid, 256, 0, stream>>>(ga);
    };

    // prep  (zero flags + h1buf + h0hist[0] = (1024+65536+32768)/4 = 24832 words)
    zero_fill<<<64, 256, 0, stream>>>((unsigned*)flags, 24832);
    bias_sum<<<16, 256, 0, stream>>>(bih0, bhh0, bih1, bhh1, bias0, bias1f);
    seg_scan<<<1, 64, 0, stream>>>(targets, meta);
    embed_gather<<<2048, 256, 0, stream>>>(targets, embw, embb, (long)BT_ * 1024);
    f2bf<<<2048, 256, 0, stream>>>(enc, encb, (long)8192 * 1024);
    f2bf<<<2048, 256, 0, stream>>>(wih0, wih0b, (long)4096 * 1024);
    f2bf<<<2048, 256, 0, stream>>>(whh0, whh0b, (long)4096 * 1024);
    pack_w1<<<2048, 256, 0, stream>>>(wih1, whh1, w1pk);
    transpose_bf16<<<dim3(32, 32), 256, 0, stream>>>(wq, wqT, 1024, 1024, 1024);
    transpose_bf16<<<dim3(32, 32), 256, 0, stream>>>(wk, wkT, 1024, 1024, 1024);
    transpose_bf16<<<dim3(32, 32), 256, 0, stream>>>(wv, wvT, 1024, 1024, 1024);
    transpose_bf16<<<dim3(64, 32), 256, 0, stream>>>(w1, w1T, 2048, 1024, 1024);
    transpose_bf16<<<dim3(32, 4), 256, 0, stream>>>(w2, w2T, 1024, 100, 128);

    // k = enc*wk + bk   (8192x1024)
    gemm(encb, 0, 0, 1024, wkT, 0, 0, 1024, (float*)0, 0, 0, 0,
         kbf, 0, 0, 1024, bk, (const float*)0, 8192, 1024, 1024, 1, 0, 1);
    // xg0 = emb*wih0^T + (bih0+bhh0)
    gemm(embb, 0, 0, 1024, wih0b, 0, 0, 1024, xg0, 0, 0, 4096,
         (bf16*)0, 0, 0, 0, bias0, (const float*)0, BT_, 4096, 1024, 1, 0, 1);

    // recurrence: persistent kernel, decoupled per-layer flag sync
    lstm_persist<<<256, 256, 0, stream>>>(whh0b, w1pk, xg0, bias1f,
                                          h0hist, h1buf, featsA, flags);

    // vT[b][d][j] = (enc[b]*wv + bv)^T   (Z=16) — into dead wih0b/whh0b region
    gemm(wvT, 0, 0, 1024, encb, (long)512 * 1024, 0, 1024, (float*)0, 0, 0, 0,
         vT, (long)1024 * 512, 0, 512, (const float*)0, bv, 1024, 512, 1024, 1, 0, 16);
    // q = h1*wq + bq
    gemm(featsA, 0, 0, 2048, wqT, 0, 0, 1024, (float*)0, 0, 0, 0,
         qbf, 0, 0, 1024, bq, (const float*)0, BT_, 1024, 1024, 1, 0, 1);
    // scores (raw) into d_out attn region, Z = 64 (b,h)
    float* attnOut = (float*)d_out + OUT0_;
    gemm(qbf, (long)241 * 1024, 256, 1024, kbf, (long)512 * 1024, 256, 1024,
         attnOut, (long)4 * 241 * 512, (long)241 * 512, 512,
         (bf16*)0, 0, 0, 0, (const float*)0, (const float*)0, 241, 512, 256, 4, 0, 64);
    attn_softmax<<<3856, 256, 0, stream>>>(attnOut, attnb, 15424);
    // ctx = attn*v -> ctx_f32 and featsA[:,1024:]
    gemm(attnb, (long)4 * 241 * 512, (long)241 * 512, 512,
         vT, (long)1024 * 512, (long)256 * 512, 512,
         ctxf, (long)241 * 1024, 256, 1024,
         featsA + 1024, (long)241 * 2048, 256, 2048,
         (const float*)0, (const float*)0, 241, 256, 512, 4, 0, 64);
    // x = tanh(feats*w1 + b1)
    gemm(featsA, 0, 0, 2048, w1T, 0, 0, 2048, (float*)0, 0, 0, 0,
         xbf, 0, 0, 1024, b1, (const float*)0, BT_, 1024, 2048, 1, 1, 1);
    // logits -> d_out[0:385600]
    gemm(xbf, 0, 0, 1024, w2T, 0, 0, 1024, (float*)d_out, 0, 0, 100,
         (bf16*)0, 0, 0, 0, b2, (const float*)0, BT_, 100, 1024, 1, 0, 1);
    logsoftmax_k<<<964, 256, 0, stream>>>((float*)d_out, BT_);

    long wn = (long)out_size - OUT0_ - OUT1_;
    if (wn > 0)
        words_fill<<<2048, 256, 0, stream>>>(meta, targets, embw, ctxf,
                                             (float*)d_out + OUT0_ + OUT1_, wn);
}

// Round 5
// 3405.937 us; speedup vs baseline: 1.1228x; 1.1228x over previous
//
#include <hip/hip_runtime.h>
#include <hip/hip_bf16.h>

typedef __bf16 bf16;
typedef __bf16 bf16x8 __attribute__((ext_vector_type(8)));
typedef float f32x4 __attribute__((ext_vector_type(4)));
typedef unsigned long long u64;
typedef u64 u64x2 __attribute__((ext_vector_type(2)));

#define B_ 16
#define T_ 241
#define H_ 1024
#define NC_ 100
#define TE_ 512
#define BT_ 3856   // B_*T_
#define OUT0_ 385600
#define OUT1_ 7897088
#define SEGCAP_ 3872

// ---------------- utility kernels ----------------

__global__ void zero_fill(unsigned* __restrict__ p, long n) {
    for (long i = (long)blockIdx.x * blockDim.x + threadIdx.x; i < n;
         i += (long)gridDim.x * blockDim.x) p[i] = 0u;
}

__global__ void bias_sum(const float* a0, const float* b0, const float* a1,
                         const float* b1, float* o0, float* o1) {
    int i = blockIdx.x * blockDim.x + threadIdx.x;
    if (i < 4096) { o0[i] = a0[i] + b0[i]; o1[i] = a1[i] + b1[i]; }
}

__global__ void f2bf(const float* __restrict__ in, bf16* __restrict__ out, long n) {
    for (long i = (long)blockIdx.x * blockDim.x + threadIdx.x; i < n;
         i += (long)gridDim.x * blockDim.x) out[i] = (bf16)in[i];
}

__global__ void embed_gather(const int* __restrict__ tg, const float* __restrict__ embw,
                             bf16* __restrict__ out, long n) {
    for (long i = (long)blockIdx.x * blockDim.x + threadIdx.x; i < n;
         i += (long)gridDim.x * blockDim.x) {
        int bt = (int)(i >> 10), d = (int)(i & 1023);
        out[i] = (bf16)embw[(long)tg[bt] * H_ + d];
    }
}

__global__ void pack_w1(const float* __restrict__ wih, const float* __restrict__ whh,
                        bf16* __restrict__ out) {
    long n = (long)4096 * 2048;
    for (long i = (long)blockIdx.x * blockDim.x + threadIdx.x; i < n;
         i += (long)gridDim.x * blockDim.x) {
        int r = (int)(i >> 11), k = (int)(i & 2047);
        float v = (k < 1024) ? wih[(long)r * 1024 + k] : whh[(long)r * 1024 + (k - 1024)];
        out[i] = (bf16)v;
    }
}

// out[n][k] = in[k][n], n < Cp (zero pad beyond C)
__global__ void transpose_bf16(const float* __restrict__ in, bf16* __restrict__ out,
                               int R, int C, int Cp) {
    __shared__ float tile[32][33];
    int k0 = blockIdx.x * 32, n0 = blockIdx.y * 32;
    int tx = threadIdx.x & 31, ty = threadIdx.x >> 5;  // 32x8
    for (int yy = ty; yy < 32; yy += 8) {
        int k = k0 + yy, n = n0 + tx;
        tile[yy][tx] = (k < R && n < C) ? in[(long)k * C + n] : 0.f;
    }
    __syncthreads();
    for (int yy = ty; yy < 32; yy += 8) {
        int n = n0 + yy, k = k0 + tx;
        if (n < Cp && k < R) out[(long)n * R + k] = (bf16)tile[tx][yy];
    }
}

// ---------------- generic A(row-major bf16) x Bt(row-major bf16) GEMM ----------------

struct GemmArgs {
    const bf16* A; long sAb; long sAh; int lda;
    const bf16* Bt; long sBb; long sBh; int ldb;
    float* C; long sCb; long sCh; int ldc;
    bf16* Cb; long sCbb; long sCbh; int ldcb;
    const float* biasCol; const float* biasRow;
    int M; int N; int K; int nh; int act;
};

__global__ void __launch_bounds__(256) gemm_bt(GemmArgs g) {
    int z = blockIdx.z;
    int zb = z / g.nh, zh = z - zb * g.nh;
    const bf16* A  = g.A  + (long)zb * g.sAb + (long)zh * g.sAh;
    const bf16* Bt = g.Bt + (long)zb * g.sBb + (long)zh * g.sBh;
    int wave = threadIdx.x >> 6, lane = threadIdx.x & 63;
    int l15 = lane & 15, kb = (lane >> 4) * 8;
    int mt0 = blockIdx.y * 4 + (wave >> 1) * 2;
    int ct0 = blockIdx.x * 4 + (wave & 1) * 2;
    const bf16* pa0 = A + (long)(mt0 * 16 + l15) * g.lda + kb;
    const bf16* pa1 = pa0 + (long)16 * g.lda;
    const bf16* pb0 = Bt + (long)(ct0 * 16 + l15) * g.ldb + kb;
    const bf16* pb1 = pb0 + (long)16 * g.ldb;
    f32x4 acc00 = {0.f,0.f,0.f,0.f}, acc01 = {0.f,0.f,0.f,0.f};
    f32x4 acc10 = {0.f,0.f,0.f,0.f}, acc11 = {0.f,0.f,0.f,0.f};
    for (int k = 0; k < g.K; k += 32) {
        bf16x8 a0 = *(const bf16x8*)(pa0 + k);
        bf16x8 a1 = *(const bf16x8*)(pa1 + k);
        bf16x8 b0 = *(const bf16x8*)(pb0 + k);
        bf16x8 b1 = *(const bf16x8*)(pb1 + k);
        acc00 = __builtin_amdgcn_mfma_f32_16x16x32_bf16(a0, b0, acc00, 0, 0, 0);
        acc01 = __builtin_amdgcn_mfma_f32_16x16x32_bf16(a0, b1, acc01, 0, 0, 0);
        acc10 = __builtin_amdgcn_mfma_f32_16x16x32_bf16(a1, b0, acc10, 0, 0, 0);
        acc11 = __builtin_amdgcn_mfma_f32_16x16x32_bf16(a1, b1, acc11, 0, 0, 0);
    }
    float* C  = g.C  ? g.C  + (long)zb * g.sCb  + (long)zh * g.sCh  : (float*)0;
    bf16*  Cb = g.Cb ? g.Cb + (long)zb * g.sCbb + (long)zh * g.sCbh : (bf16*)0;
    int rbase = (lane >> 4) * 4;
#pragma unroll
    for (int i = 0; i < 2; i++) {
#pragma unroll
        for (int j = 0; j < 2; j++) {
            f32x4 av = i ? (j ? acc11 : acc10) : (j ? acc01 : acc00);
            int colg = (ct0 + j) * 16 + l15;
            if (colg >= g.N) continue;
            float bc = g.biasCol ? g.biasCol[colg] : 0.f;
#pragma unroll
            for (int r = 0; r < 4; r++) {
                int rowg = (mt0 + i) * 16 + rbase + r;
                if (rowg >= g.M) continue;
                float val = av[r] + bc;
                if (g.biasRow) val += g.biasRow[rowg];
                if (g.act == 1) val = tanhf(val);
                if (C)  C[(long)rowg * g.ldc + colg] = val;
                if (Cb) Cb[(long)rowg * g.ldcb + colg] = (bf16)val;
            }
        }
    }
}

// ---------------- persistent LSTM recurrence (decoupled, hot ring) ----------------
// blocks 0..127: layer0 (8 units each); 128..255: layer1.
// h0 -> 8-slot ring (256KB, stays L3-hot). L0 throttles on L1 >= s-7 (WAR).
// L1 waves 0-1 wait only on L0 (h0 half of K); waves 2-3 on L1 peers (h1 half).
// flags[0..127]=L0 progress, flags[128..255]=L1 progress. Dense 4B flags.

__device__ __forceinline__ u64 cload(const u64* p) {
    return __hip_atomic_load(p, __ATOMIC_RELAXED, __HIP_MEMORY_SCOPE_AGENT);
}
__device__ __forceinline__ void cstore(unsigned* p, unsigned v) {
    __hip_atomic_store(p, v, __ATOMIC_RELAXED, __HIP_MEMORY_SCOPE_AGENT);
}
__device__ __forceinline__ unsigned pack2(bf16 a, bf16 b) {
    union { bf16 h[2]; unsigned u; } x; x.h[0] = a; x.h[1] = b; return x.u;
}
__device__ __forceinline__ unsigned fload(const unsigned* p) {
    return __hip_atomic_load(p, __ATOMIC_RELAXED, __HIP_MEMORY_SCOPE_AGENT);
}

// wave-cooperative: wait until all f0[0..127] >= t0 (and f1[0..127] >= t1 if f1)
__device__ __forceinline__ void pollf(const unsigned* f0, unsigned t0,
                                      const unsigned* f1, unsigned t1, int lane) {
    for (;;) {
        unsigned a = fload(f0 + 2 * lane);
        unsigned b = fload(f0 + 2 * lane + 1);
        bool ok = (a >= t0) && (b >= t0);
        if (f1) {
            unsigned c = fload(f1 + 2 * lane);
            unsigned d = fload(f1 + 2 * lane + 1);
            ok = ok && (c >= t1) && (d >= t1);
        }
        if (__all((int)ok)) break;
        __builtin_amdgcn_s_sleep(1);
    }
    asm volatile("" ::: "memory");
}

__global__ void __launch_bounds__(256, 1) lstm_persist(
    const bf16* __restrict__ Whh0, const bf16* __restrict__ W1pk,
    const float* __restrict__ xg0, const float* __restrict__ bias1,
    bf16* __restrict__ h0ring,      // [8][16][1024] ring, slot0 zeroed
    bf16* __restrict__ h1buf,       // [2][16][1024], zeroed
    bf16* __restrict__ featsA, unsigned* __restrict__ flags) {
    int blk = blockIdx.x;
    bool isL1 = blk >= 128;
    int bL = isL1 ? blk - 128 : blk;
    int ub = bL * 8;
    int wave = threadIdx.x >> 6, lane = threadIdx.x & 63;
    int l15 = lane & 15, kb = (lane >> 4) * 8;
    int rl0 = l15, rl1 = 16 + l15;
    int grow0 = (rl0 >> 3) * 1024 + ub + (rl0 & 7);
    int grow1 = (rl1 >> 3) * 1024 + ub + (rl1 & 7);

    __shared__ float red[4][32][17];

    int t = threadIdx.x;
    int pb = t >> 2, up = (t & 3) * 2;        // pointwise: 64 threads, 2 units
    float cr0 = 0.f, cr1 = 0.f;
    int rb = (lane >> 4) * 4;

    if (!isL1) {
        f32x4 wa[8], wb[8];
        const bf16* p0 = Whh0 + (long)grow0 * 1024 + wave * 256 + kb;
        const bf16* p1 = Whh0 + (long)grow1 * 1024 + wave * 256 + kb;
#pragma unroll
        for (int i = 0; i < 8; i++) {
            wa[i] = *(const f32x4*)(p0 + 32 * i);
            wb[i] = *(const f32x4*)(p1 + 32 * i);
            asm volatile("" : "+v"(wa[i]), "+v"(wb[i]));
        }
        for (int s = 0; s < 241; s++) {
            // xg0 prefetch for this step — issued BEFORE the poll, lands during spin
            float2 x0, x1, x2, x3;
            if (t < 64) {
                const float* xp = xg0 + ((long)pb * 241 + s) * 4096 + ub + up;
                x0 = *(const float2*)(xp);
                x1 = *(const float2*)(xp + 1024);
                x2 = *(const float2*)(xp + 2048);
                x3 = *(const float2*)(xp + 3072);
            }
            unsigned war = (s > 7) ? (unsigned)(s - 7) : 0u;
            pollf(flags, (unsigned)s, flags + 128, war, lane);
            const bf16* pa = h0ring + ((long)(s & 7) << 14) + l15 * 1024 + wave * 256 + kb;
            u64x2 hf[8];
#pragma unroll
            for (int i = 0; i < 8; i++) {
                const u64* q = (const u64*)(pa + 32 * i);
                hf[i].x = cload(q); hf[i].y = cload(q + 1);
            }
            f32x4 acc0 = {0.f,0.f,0.f,0.f}, acc1 = {0.f,0.f,0.f,0.f};
#pragma unroll
            for (int i = 0; i < 8; i++) {
                bf16x8 a = __builtin_bit_cast(bf16x8, hf[i]);
                acc0 = __builtin_amdgcn_mfma_f32_16x16x32_bf16(a, __builtin_bit_cast(bf16x8, wa[i]), acc0, 0, 0, 0);
                acc1 = __builtin_amdgcn_mfma_f32_16x16x32_bf16(a, __builtin_bit_cast(bf16x8, wb[i]), acc1, 0, 0, 0);
            }
#pragma unroll
            for (int r = 0; r < 4; r++) {
                red[wave][rl0][rb + r] = acc0[r];
                red[wave][rl1][rb + r] = acc1[r];
            }
            __syncthreads();
            if (t < 64) {
                float g[2][4];
#pragma unroll
                for (int uu = 0; uu < 2; uu++)
#pragma unroll
                    for (int gi = 0; gi < 4; gi++) {
                        float v = 0.f;
#pragma unroll
                        for (int w = 0; w < 4; w++) v += red[w][gi * 8 + up + uu][pb];
                        g[uu][gi] = v;
                    }
                bf16 hv[2];
#pragma unroll
                for (int uu = 0; uu < 2; uu++) {
                    float gi_ = g[uu][0] + (uu ? x0.y : x0.x);
                    float gf_ = g[uu][1] + (uu ? x1.y : x1.x);
                    float gg_ = g[uu][2] + (uu ? x2.y : x2.x);
                    float go_ = g[uu][3] + (uu ? x3.y : x3.x);
                    float si = 1.f / (1.f + expf(-gi_));
                    float sf = 1.f / (1.f + expf(-gf_));
                    float so = 1.f / (1.f + expf(-go_));
                    float& cr = uu ? cr1 : cr0;
                    cr = sf * cr + si * tanhf(gg_);
                    hv[uu] = (bf16)(so * tanhf(cr));
                }
                cstore((unsigned*)(h0ring + ((long)((s + 1) & 7) << 14) + pb * 1024 + ub + up),
                       pack2(hv[0], hv[1]));
                asm volatile("s_waitcnt vmcnt(0)" ::: "memory");
                if (t == 0) cstore(flags + blk, (unsigned)(s + 1));
            }
        }
    } else {
        f32x4 wa[16], wb[16];
        const bf16* p0 = W1pk + (long)grow0 * 2048 + wave * 512 + kb;
        const bf16* p1 = W1pk + (long)grow1 * 2048 + wave * 512 + kb;
#pragma unroll
        for (int i = 0; i < 16; i++) {
            wa[i] = *(const f32x4*)(p0 + 32 * i);
            wb[i] = *(const f32x4*)(p1 + 32 * i);
            asm volatile("" : "+v"(wa[i]), "+v"(wb[i]));
        }
        // hoist bias out of the loop
        float2 b0, b1, b2, b3;
        if (t < 64) {
            b0 = *(const float2*)(bias1 + ub + up);
            b1 = *(const float2*)(bias1 + 1024 + ub + up);
            b2 = *(const float2*)(bias1 + 2048 + ub + up);
            b3 = *(const float2*)(bias1 + 3072 + ub + up);
        }
        for (int s = 1; s <= 241; s++) {
            // waves 0-1 need only h0 (L0 runs ahead); waves 2-3 need h1 peers
            if (wave < 2) pollf(flags, (unsigned)s, (const unsigned*)0, 0u, lane);
            else pollf(flags + 128, (unsigned)(s - 1), (const unsigned*)0, 0u, lane);
            const bf16* pa = (wave < 2)
                ? h0ring + ((long)(s & 7) << 14) + l15 * 1024 + wave * 512 + kb
                : h1buf + (long)((s & 1) << 14) + l15 * 1024 + (wave - 2) * 512 + kb;
            u64x2 hf[16];
#pragma unroll
            for (int i = 0; i < 16; i++) {
                const u64* q = (const u64*)(pa + 32 * i);
                hf[i].x = cload(q); hf[i].y = cload(q + 1);
            }
            f32x4 acc0 = {0.f,0.f,0.f,0.f}, acc1 = {0.f,0.f,0.f,0.f};
#pragma unroll
            for (int i = 0; i < 16; i++) {
                bf16x8 a = __builtin_bit_cast(bf16x8, hf[i]);
                acc0 = __builtin_amdgcn_mfma_f32_16x16x32_bf16(a, __builtin_bit_cast(bf16x8, wa[i]), acc0, 0, 0, 0);
                acc1 = __builtin_amdgcn_mfma_f32_16x16x32_bf16(a, __builtin_bit_cast(bf16x8, wb[i]), acc1, 0, 0, 0);
            }
#pragma unroll
            for (int r = 0; r < 4; r++) {
                red[wave][rl0][rb + r] = acc0[r];
                red[wave][rl1][rb + r] = acc1[r];
            }
            __syncthreads();
            if (t < 64) {
                float g[2][4];
#pragma unroll
                for (int uu = 0; uu < 2; uu++)
#pragma unroll
                    for (int gi = 0; gi < 4; gi++) {
                        float v = 0.f;
#pragma unroll
                        for (int w = 0; w < 4; w++) v += red[w][gi * 8 + up + uu][pb];
                        g[uu][gi] = v;
                    }
                bf16 hv[2];
#pragma unroll
                for (int uu = 0; uu < 2; uu++) {
                    float gi_ = g[uu][0] + (uu ? b0.y : b0.x);
                    float gf_ = g[uu][1] + (uu ? b1.y : b1.x);
                    float gg_ = g[uu][2] + (uu ? b2.y : b2.x);
                    float go_ = g[uu][3] + (uu ? b3.y : b3.x);
                    float si = 1.f / (1.f + expf(-gi_));
                    float sf = 1.f / (1.f + expf(-gf_));
                    float so = 1.f / (1.f + expf(-go_));
                    float& cr = uu ? cr1 : cr0;
                    cr = sf * cr + si * tanhf(gg_);
                    hv[uu] = (bf16)(so * tanhf(cr));
                }
                unsigned pv = pack2(hv[0], hv[1]);
                cstore((unsigned*)(h1buf + (long)(((s + 1) & 1) << 14) + pb * 1024 + ub + up), pv);
                asm volatile("s_waitcnt vmcnt(0)" ::: "memory");
                if (t == 0) cstore(flags + blk, (unsigned)s);
                // off the critical path: plain store, drained at kernel end
                *(unsigned*)(featsA + ((long)pb * 241 + (s - 1)) * 2048 + ub + up) = pv;
            }
        }
    }
}

// ---------------- softmaxes ----------------

__global__ void __launch_bounds__(256) attn_softmax(float* __restrict__ attn,
                                                    bf16* __restrict__ attnb, int nrows) {
    int row = blockIdx.x * 4 + (threadIdx.x >> 6);
    int lane = threadIdx.x & 63;
    if (row >= nrows) return;
    float* p = attn + (long)row * 512;
    float v[8];
    float m = -1e30f;
#pragma unroll
    for (int j = 0; j < 8; j++) { v[j] = p[lane + 64 * j] * 0.0625f; m = fmaxf(m, v[j]); }
    for (int o = 32; o; o >>= 1) m = fmaxf(m, __shfl_xor(m, o));
    float ssum = 0.f;
#pragma unroll
    for (int j = 0; j < 8; j++) { v[j] = expf(v[j] - m); ssum += v[j]; }
    for (int o = 32; o; o >>= 1) ssum += __shfl_xor(ssum, o);
    float inv = 1.f / ssum;
#pragma unroll
    for (int j = 0; j < 8; j++) {
        float a = v[j] * inv;
        p[lane + 64 * j] = a;
        attnb[(long)row * 512 + lane + 64 * j] = (bf16)a;
    }
}

__global__ void __launch_bounds__(256) logsoftmax_k(float* __restrict__ out, int nrows) {
    int row = blockIdx.x * 4 + (threadIdx.x >> 6);
    int lane = threadIdx.x & 63;
    if (row >= nrows) return;
    float* p = out + (long)row * 100;
    float v0 = lane < 100 ? p[lane] : -1e30f;
    float v1 = lane < 36 ? p[64 + lane] : -1e30f;
    float m = fmaxf(v0, v1);
    for (int o = 32; o; o >>= 1) m = fmaxf(m, __shfl_xor(m, o));
    float s = (lane < 100 ? expf(v0 - m) : 0.f) + (lane < 36 ? expf(v1 - m) : 0.f);
    for (int o = 32; o; o >>= 1) s += __shfl_xor(s, o);
    float lg = m + logf(s);
    if (lane < 100) p[lane] = v0 - lg;
    if (lane < 36) p[64 + lane] = v1 - lg;
}

// ---------------- words ----------------

__global__ void seg_scan(const int* __restrict__ tg, int* __restrict__ meta) {
    __shared__ int st[16][242], ln[16][242];
    __shared__ int cnt[16], rmax[16], off[17];
    int b = threadIdx.x;
    if (b < 16) {
        const int* tok = tg + b * 241 + 1;
        int start = 0, n = 0, mx = 0; bool broke = false;
        for (int t = 0; t < 240; t++) {
            int v = tok[t];
            if (v == 1 || v == 2) {
                st[b][n] = start; ln[b][n] = t - start;
                if (t - start > mx) mx = t - start;
                n++; start = t + 1;
                if (v == 2) { broke = true; break; }
            }
        }
        if (!broke && start < 240) {
            st[b][n] = start; ln[b][n] = 240 - start;
            if (240 - start > mx) mx = 240 - start;
            n++;
        }
        cnt[b] = n; rmax[b] = mx;
    }
    __syncthreads();
    if (threadIdx.x == 0) {
        int tot = 0, mx = 0;
        for (int i = 0; i < 16; i++) { off[i] = tot; tot += cnt[i]; if (rmax[i] > mx) mx = rmax[i]; }
        off[16] = tot; meta[0] = tot; meta[1] = mx;
    }
    __syncthreads();
    if (b < 16) {
        int* segb = meta + 2; int* segs = segb + SEGCAP_; int* segl = segs + SEGCAP_;
        int o = off[b];
        for (int i = 0; i < cnt[b]; i++) { segb[o + i] = b; segs[o + i] = st[b][i]; segl[o + i] = ln[b][i]; }
    }
}

__global__ void words_fill(const int* __restrict__ meta, const int* __restrict__ tg,
                           const float* __restrict__ embw, const float* __restrict__ ctxf,
                           float* __restrict__ out2, long nelem) {
    int N = meta[0], mx = meta[1];
    const int* segb = meta + 2;
    const int* segs = segb + SEGCAP_;
    const int* segl = segs + SEGCAP_;
    unsigned wl = (unsigned)mx * 2048u;
    if (wl == 0) wl = 1u;
    for (long ee = (long)blockIdx.x * blockDim.x + threadIdx.x; ee < nelem;
         ee += (long)gridDim.x * blockDim.x) {
        unsigned e = (unsigned)ee;
        unsigned n = e / wl, rem = e - n * wl;
        unsigned l = rem >> 11, d = rem & 2047u;
        float val = 0.f;
        if ((int)n < N && (int)l < segl[n]) {
            int b = segb[n]; int tp = segs[n] + (int)l;  // index in sliced [0,240)
            if (d < 1024u) val = embw[(long)tg[b * 241 + tp + 1] * H_ + d];
            else val = ctxf[((long)b * 241 + tp) * H_ + (d - 1024u)];
        }
        out2[ee] = val;
    }
}

// ---------------- host ----------------

extern "C" void kernel_launch(void* const* d_in, const int* in_sizes, int n_in,
                              void* d_out, int out_size, void* d_ws, size_t ws_size,
                              hipStream_t stream) {
    const int*   targets = (const int*)d_in[0];
    const float* enc  = (const float*)d_in[1];
    const float* embw = (const float*)d_in[2];
    const float* wih0 = (const float*)d_in[3];
    const float* whh0 = (const float*)d_in[4];
    const float* bih0 = (const float*)d_in[5];
    const float* bhh0 = (const float*)d_in[6];
    const float* wih1 = (const float*)d_in[7];
    const float* whh1 = (const float*)d_in[8];
    const float* bih1 = (const float*)d_in[9];
    const float* bhh1 = (const float*)d_in[10];
    const float* wq = (const float*)d_in[11];
    const float* bq = (const float*)d_in[12];
    const float* wk = (const float*)d_in[13];
    const float* bk = (const float*)d_in[14];
    const float* wv = (const float*)d_in[15];
    const float* bv = (const float*)d_in[16];
    const float* w1 = (const float*)d_in[17];
    const float* b1 = (const float*)d_in[18];
    const float* w2 = (const float*)d_in[19];
    const float* b2 = (const float*)d_in[20];

    char* ws = (char*)d_ws;
    size_t off = 0;
    auto alloc = [&](size_t bytes) {
        char* p = ws + off; off += (bytes + 255) & ~(size_t)255; return p;
    };
    // zero-init region (contiguous): flags, h1buf, h0ring[0]
    unsigned* flags = (unsigned*)alloc(1024);                 // 256 dense flags
    bf16* h1buf  = (bf16*)alloc(2 * 16 * 1024 * 2);           // 64 KB
    bf16* h0ring = (bf16*)alloc((size_t)8 * 16 * 1024 * 2);   // 256 KB ring
    float* bias0 = (float*)alloc(16384);
    float* bias1f = (float*)alloc(16384);
    int* meta = (int*)alloc((2 + 3 * SEGCAP_) * 4);
    bf16* kbf = (bf16*)alloc((size_t)8192 * 1024 * 2);
    bf16* wqT = (bf16*)alloc((size_t)1024 * 1024 * 2);
    bf16* w1T = (bf16*)alloc((size_t)1024 * 2048 * 2);
    bf16* w2T = (bf16*)alloc((size_t)128 * 1024 * 2);
    bf16* featsA = (bf16*)alloc((size_t)3920 * 2048 * 2);
    char* regB = alloc(63176704);              // xg0; reused after recurrence
    float* xg0  = (float*)regB;
    bf16* qbf   = (bf16*)regB;                           // 3920*1024*2 = 8028160
    bf16* attnb = (bf16*)(regB + 8028160);               // 15488*512*2 = 15859712
    float* ctxf = (float*)(regB + 8028160 + 15859712);   // 3856*1024*4 = 15794176
    bf16* xbf   = (bf16*)(regB + 39682048);              // 3920*1024*2
    bf16* embb  = (bf16*)alloc((size_t)3920 * 1024 * 2);
    bf16* encb  = (bf16*)alloc((size_t)8192 * 1024 * 2);
    bf16* wih0b = (bf16*)alloc((size_t)4096 * 1024 * 2);
    bf16* whh0b = (bf16*)alloc((size_t)4096 * 1024 * 2);
    bf16* w1pk  = (bf16*)alloc((size_t)4096 * 2048 * 2);
    bf16* wkT = (bf16*)alloc((size_t)1024 * 1024 * 2);
    bf16* wvT = (bf16*)alloc((size_t)1024 * 1024 * 2);
    // vT (16 MB) reuses wih0b+whh0b after the recurrence (both dead by then)
    bf16* vT = wih0b;
    (void)ws_size; (void)in_sizes; (void)n_in;

    auto gemm = [&](const bf16* A, long sAb, long sAh, int lda,
                    const bf16* Bt, long sBb, long sBh, int ldb,
                    float* C, long sCb, long sCh, int ldc,
                    bf16* Cb, long sCbb, long sCbh, int ldcb,
                    const float* bc, const float* br,
                    int M, int N, int K, int nh, int act, int Z) {
        GemmArgs ga{A, sAb, sAh, lda, Bt, sBb, sBh, ldb, C, sCb, sCh, ldc,
                    Cb, sCbb, sCbh, ldcb, bc, br, M, N, K, nh, act};
        dim3 grid((N + 63) / 64, (M + 63) / 64, Z);
        gemm_bt<<<grid, 256, 0, stream>>>(ga);
    };

    // prep  (zero flags + h1buf + h0ring[0] = (1024+65536+32768)/4 = 24832 words)
    zero_fill<<<64, 256, 0, stream>>>((unsigned*)flags, 24832);
    bias_sum<<<16, 256, 0, stream>>>(bih0, bhh0, bih1, bhh1, bias0, bias1f);
    seg_scan<<<1, 64, 0, stream>>>(targets, meta);
    embed_gather<<<2048, 256, 0, stream>>>(targets, embw, embb, (long)BT_ * 1024);
    f2bf<<<2048, 256, 0, stream>>>(enc, encb, (long)8192 * 1024);
    f2bf<<<2048, 256, 0, stream>>>(wih0, wih0b, (long)4096 * 1024);
    f2bf<<<2048, 256, 0, stream>>>(whh0, whh0b, (long)4096 * 1024);
    pack_w1<<<2048, 256, 0, stream>>>(wih1, whh1, w1pk);
    transpose_bf16<<<dim3(32, 32), 256, 0, stream>>>(wq, wqT, 1024, 1024, 1024);
    transpose_bf16<<<dim3(32, 32), 256, 0, stream>>>(wk, wkT, 1024, 1024, 1024);
    transpose_bf16<<<dim3(32, 32), 256, 0, stream>>>(wv, wvT, 1024, 1024, 1024);
    transpose_bf16<<<dim3(64, 32), 256, 0, stream>>>(w1, w1T, 2048, 1024, 1024);
    transpose_bf16<<<dim3(32, 4), 256, 0, stream>>>(w2, w2T, 1024, 100, 128);

    // k = enc*wk + bk   (8192x1024)
    gemm(encb, 0, 0, 1024, wkT, 0, 0, 1024, (float*)0, 0, 0, 0,
         kbf, 0, 0, 1024, bk, (const float*)0, 8192, 1024, 1024, 1, 0, 1);
    // xg0 = emb*wih0^T + (bih0+bhh0)
    gemm(embb, 0, 0, 1024, wih0b, 0, 0, 1024, xg0, 0, 0, 4096,
         (bf16*)0, 0, 0, 0, bias0, (const float*)0, BT_, 4096, 1024, 1, 0, 1);

    // recurrence: persistent kernel, decoupled per-layer flag sync + hot ring
    lstm_persist<<<256, 256, 0, stream>>>(whh0b, w1pk, xg0, bias1f,
                                          h0ring, h1buf, featsA, flags);

    // vT[b][d][j] = (enc[b]*wv + bv)^T   (Z=16) — into dead wih0b/whh0b region
    gemm(wvT, 0, 0, 1024, encb, (long)512 * 1024, 0, 1024, (float*)0, 0, 0, 0,
         vT, (long)1024 * 512, 0, 512, (const float*)0, bv, 1024, 512, 1024, 1, 0, 16);
    // q = h1*wq + bq
    gemm(featsA, 0, 0, 2048, wqT, 0, 0, 1024, (float*)0, 0, 0, 0,
         qbf, 0, 0, 1024, bq, (const float*)0, BT_, 1024, 1024, 1, 0, 1);
    // scores (raw) into d_out attn region, Z = 64 (b,h)
    float* attnOut = (float*)d_out + OUT0_;
    gemm(qbf, (long)241 * 1024, 256, 1024, kbf, (long)512 * 1024, 256, 1024,
         attnOut, (long)4 * 241 * 512, (long)241 * 512, 512,
         (bf16*)0, 0, 0, 0, (const float*)0, (const float*)0, 241, 512, 256, 4, 0, 64);
    attn_softmax<<<3856, 256, 0, stream>>>(attnOut, attnb, 15424);
    // ctx = attn*v -> ctx_f32 and featsA[:,1024:]
    gemm(attnb, (long)4 * 241 * 512, (long)241 * 512, 512,
         vT, (long)1024 * 512, (long)256 * 512, 512,
         ctxf, (long)241 * 1024, 256, 1024,
         featsA + 1024, (long)241 * 2048, 256, 2048,
         (const float*)0, (const float*)0, 241, 256, 512, 4, 0, 64);
    // x = tanh(feats*w1 + b1)
    gemm(featsA, 0, 0, 2048, w1T, 0, 0, 2048, (float*)0, 0, 0, 0,
         xbf, 0, 0, 1024, b1, (const float*)0, BT_, 1024, 2048, 1, 1, 1);
    // logits -> d_out[0:385600]
    gemm(xbf, 0, 0, 1024, w2T, 0, 0, 1024, (float*)d_out, 0, 0, 100,
         (bf16*)0, 0, 0, 0, b2, (const float*)0, BT_, 100, 1024, 1, 0, 1);
    logsoftmax_k<<<964, 256, 0, stream>>>((float*)d_out, BT_);

    long wn = (long)out_size - OUT0_ - OUT1_;
    if (wn > 0)
        words_fill<<<2048, 256, 0, stream>>>(meta, targets, embw, ctxf,
                                             (float*)d_out + OUT0_ + OUT1_, wn);
}